// Round 10
// baseline (173.643 us; speedup 1.0000x reference)
//
#include <hip/hip_runtime.h>

// ---------------------------------------------------------------------------
// Round 10: DIAGNOSTIC. Exact round-6 pipeline, but conv repeats its entire
// tile pass REPS=4 times (identical overwrites, barrier-separated) so the
// conv kernel's steady-state counters finally appear above the harness's
// ~40-43 us poison-fill dispatches in the rocprof top-5.
// ---------------------------------------------------------------------------

#define A_MORR 0.8578f
#define R_MORR 0.8578f
#define TR_C1 (A_MORR * A_MORR + R_MORR * R_MORR)
#define TR_C2 (-2.0f * A_MORR * R_MORR)
#define TR_C3 (1.0f + (A_MORR * R_MORR) * (A_MORR * R_MORR))
#define BN_EPS 1e-5f

#define NPIX 65536
#define X2_LO 26112          // 6*34*128: lo plane offset
#define SMEM_BYTES 52224
#define NBLK 512
#define REPS 4

typedef __attribute__((ext_vector_type(8))) short bf16x8;
typedef __attribute__((ext_vector_type(16))) float f32x16;

__device__ __forceinline__ void bf16split(float s, unsigned short& h, unsigned short& l) {
    union { float f; unsigned u; } cv; cv.f = s;
    unsigned r = (cv.u + 0x7fffu + ((cv.u >> 16) & 1u)) & 0xffff0000u;
    h = (unsigned short)(r >> 16);
    union { unsigned u; float f; } hv; hv.u = r;
    float lo = s - hv.f;
    cv.f = lo;
    unsigned r2 = cv.u + 0x7fffu + ((cv.u >> 16) & 1u);
    l = (unsigned short)(r2 >> 16);
}

// ---------------------------------------------------------------------------
// Kernel A: fragment-ready bf16 hi/lo weights.
// wfrag[off*8 + ks*2 + mt][prec][lane][8ch] : 72 * 2048 B
// ---------------------------------------------------------------------------
__global__ __launch_bounds__(256) void prep_kernel(const float* __restrict__ w,
                                                   char* __restrict__ wfrag) {
    int gtid = blockIdx.x * 256 + threadIdx.x;
    if (gtid < 36864) {
        int j    = gtid & 7;
        int lane = (gtid >> 3) & 63;
        int okm  = gtid >> 9;
        int mt   = okm & 1;
        int ks   = (okm >> 1) & 3;
        int off  = okm >> 3;
        int oc   = mt * 32 + (lane & 31);
        int c    = ks * 16 + (lane >> 5) * 8 + j;
        int kg   = c * 9 + off;
        float val = w[(oc >> 3) * 576 + (kg >> 3) * 8 + ((oc - kg) & 7)];
        unsigned short h, l;
        bf16split(val, h, l);
        ((unsigned short*)(wfrag + okm * 2048))[lane * 8 + j] = h;
        ((unsigned short*)(wfrag + okm * 2048 + 1024))[lane * 8 + j] = l;
    }
}

// ---------------------------------------------------------------------------
// Kernel B: round-6 conv (waves = wmt x kh x py, kh merge through LDS),
// wrapped in a REPS loop. grid (8,64), block 512, 2 blocks/CU.
// LDS x2: [6 rows][34 cols][64 ch] bf16 hi+lo, granule-XOR swizzle.
// ---------------------------------------------------------------------------
__global__ __launch_bounds__(512, 2) void conv_kernel(const float* __restrict__ x,
                                                      const char* __restrict__ wfrag,
                                                      float* __restrict__ out,
                                                      float* __restrict__ partials) {
    const int rt  = blockIdx.x;
    const int b   = blockIdx.y;
    const int bid = b * 8 + rt;
    const int tid = threadIdx.x;

    __shared__ __align__(16) char smem[SMEM_BYTES];

    const int lane = tid & 63;
    const int wv   = tid >> 6;
    const int wmt  = wv & 1;
    const int kh   = (wv >> 1) & 1;
    const int py   = wv >> 2;
    const int col  = lane & 31;
    const int hs   = lane >> 5;
    const int rowb = py * 2;

    for (int rep = 0; rep < REPS; ++rep) {
        __syncthreads();                 // guard: prior rep's smem reads done

        // ---- zero halo cols ----
        if (tid < 192) {
            int prec = tid & 1;
            int g    = (tid >> 1) & 7;
            int rc   = tid >> 4;
            int r    = rc >> 1;
            int c    = (rc & 1) ? 33 : 0;
            *(uint4*)(smem + prec * X2_LO + ((r * 34 + c) << 7) + (g << 4)) = uint4{0, 0, 0, 0};
        }

        // ---- stage x^2 (hi/lo) ----
        {
            const int rh  = tid & 1;
            const int co  = (tid >> 1) & 7;
            const int chp = tid >> 4;
            const float* xb = x + (size_t)(b * 64 + 2 * chp) * 1024;
#pragma unroll
            for (int r3 = 0; r3 < 3; ++r3) {
                int rr = rh * 3 + r3;
                int gr = rt * 4 - 1 + rr;
                float4 a0 = {0.f, 0.f, 0.f, 0.f}, a1 = {0.f, 0.f, 0.f, 0.f};
                if (gr >= 0 && gr < 32) {
                    const float* rp = xb + gr * 32 + co * 4;
                    a0 = *(const float4*)rp;
                    a1 = *(const float4*)(rp + 1024);
                }
                float s0[4] = {a0.x * a0.x, a0.y * a0.y, a0.z * a0.z, a0.w * a0.w};
                float s1[4] = {a1.x * a1.x, a1.y * a1.y, a1.z * a1.z, a1.w * a1.w};
#pragma unroll
                for (int i = 0; i < 4; ++i) {
                    unsigned short h0, l0, h1, l1;
                    bf16split(s0[i], h0, l0);
                    bf16split(s1[i], h1, l1);
                    int c    = 1 + co * 4 + i;
                    int base = ((rr * 34 + c) << 7) + (((chp >> 2) ^ (c & 7)) << 4)
                             + ((chp & 3) << 2);
                    *(unsigned*)(smem + base)         = (unsigned)h0 | ((unsigned)h1 << 16);
                    *(unsigned*)(smem + X2_LO + base) = (unsigned)l0 | ((unsigned)l1 << 16);
                }
            }
        }
        __syncthreads();

        // ---- K loop ----
        f32x16 acc0, acc1;
#pragma unroll
        for (int i = 0; i < 16; ++i) { acc0[i] = 0.f; acc1[i] = 0.f; }

        const char* wbase = wfrag + wmt * 2048 + (size_t)lane * 16;

#pragma unroll
        for (int dj = 0; dj < 3; ++dj) {
            const int c  = col + dj;
            const int c7 = c & 7;
#pragma unroll
            for (int ksi = 0; ksi < 2; ++ksi) {
                const int ks = kh * 2 + ksi;
                const int g  = ((ks * 2 + hs) ^ c7) << 4;
                bf16x8 bh[4], bl[4];
#pragma unroll
                for (int rr = 0; rr < 4; ++rr) {
                    const char* sp = smem + (((rowb + rr) * 34 + c) << 7) + g;
                    bh[rr] = *(const bf16x8*)sp;
                    bl[rr] = *(const bf16x8*)(sp + X2_LO);
                }
#pragma unroll
                for (int di = 0; di < 3; ++di) {
                    const char* wp = wbase + (di * 3 + dj) * 16384 + ks * 4096;
                    bf16x8 ah = *(const bf16x8*)wp;
                    bf16x8 al = *(const bf16x8*)(wp + 1024);
                    acc0 = __builtin_amdgcn_mfma_f32_32x32x16_bf16(ah, bh[di],     acc0, 0, 0, 0);
                    acc1 = __builtin_amdgcn_mfma_f32_32x32x16_bf16(ah, bh[di + 1], acc1, 0, 0, 0);
                    acc0 = __builtin_amdgcn_mfma_f32_32x32x16_bf16(ah, bl[di],     acc0, 0, 0, 0);
                    acc1 = __builtin_amdgcn_mfma_f32_32x32x16_bf16(ah, bl[di + 1], acc1, 0, 0, 0);
                    acc0 = __builtin_amdgcn_mfma_f32_32x32x16_bf16(al, bh[di],     acc0, 0, 0, 0);
                    acc1 = __builtin_amdgcn_mfma_f32_32x32x16_bf16(al, bh[di + 1], acc1, 0, 0, 0);
                }
            }
        }

        // ---- merge K-halves, tr on kh==0 ----
        float* mergef = (float*)smem;
        __syncthreads();                           // S1
        {
            const int slot = (wmt * 2 + py) * 2;
            if (kh == 1) {
#pragma unroll
                for (int r = 0; r < 16; ++r) {
                    mergef[((slot + 0) * 16 + r) * 64 + lane] = acc0[r];
                    mergef[((slot + 1) * 16 + r) * 64 + lane] = acc1[r];
                }
            }
            __syncthreads();                       // S2
            if (kh == 0) {
#pragma unroll
                for (int r = 0; r < 16; ++r) {
                    float p0 = acc0[r] + mergef[((slot + 0) * 16 + r) * 64 + lane];
                    float p1 = acc1[r] + mergef[((slot + 1) * 16 + r) * 64 + lane];
                    float c0 = __cosf(p0);
                    float c1 = __cosf(p1);
                    acc0[r] = fmaf(TR_C2, c0, TR_C1) / fmaf(TR_C2, c0, TR_C3);
                    acc1[r] = fmaf(TR_C2, c1, TR_C1) / fmaf(TR_C2, c1, TR_C3);
                }
            }
        }
        __syncthreads();                           // S3

        // ---- per-channel partials + store ----
        float* red1 = mergef;                      // [64][66]
        float* red2 = red1 + 64 * 66;              // [64][66]
        if (kh == 0) {
#pragma unroll
            for (int r = 0; r < 16; ++r) {
                int ocl  = (r & 3) + 8 * (r >> 2) + 4 * hs;
                float t0 = acc0[r], t1 = acc1[r];
                int ri = (wmt * 32 + ocl) * 66 + py * 32 + col;
                red1[ri] = t0 + t1;
                red2[ri] = t0 * t0 + t1 * t1;
            }
            const size_t outbase = ((size_t)b * 64 + wmt * 32) * 1024 + rt * 128;
#pragma unroll
            for (int r = 0; r < 16; ++r) {
                int ocl  = (r & 3) + 8 * (r >> 2) + 4 * hs;
                size_t o = outbase + (size_t)ocl * 1024 + py * 64 + col;
                out[o]      = acc0[r];
                out[o + 32] = acc1[r];
            }
        }
        __syncthreads();                           // S4
        if (tid < 64) {
            float s1 = 0.f, s2 = 0.f;
#pragma unroll
            for (int q = 0; q < 64; ++q) {
                s1 += red1[tid * 66 + q];
                s2 += red2[tid * 66 + q];
            }
            partials[(size_t)tid * NBLK + bid]        = s1;
            partials[(size_t)(64 + tid) * NBLK + bid] = s2;
        }
    }
}

// ---------------------------------------------------------------------------
__global__ __launch_bounds__(512) void stats_kernel(const float* __restrict__ partials,
                                                    const float* __restrict__ gamma,
                                                    const float* __restrict__ beta,
                                                    float* __restrict__ ss) {
    const int c   = blockIdx.x;
    const int tid = threadIdx.x;
    __shared__ float r1[512], r2[512];
    r1[tid] = partials[(size_t)c * NBLK + tid];
    r2[tid] = partials[(size_t)(64 + c) * NBLK + tid];
    __syncthreads();
#pragma unroll
    for (int s = 256; s > 0; s >>= 1) {
        if (tid < s) {
            r1[tid] += r1[tid + s];
            r2[tid] += r2[tid + s];
        }
        __syncthreads();
    }
    if (tid == 0) {
        const float invN = 1.0f / (float)NPIX;
        float mean = r1[0] * invN;
        float var  = r2[0] * invN - mean * mean;
        float sc   = gamma[c] * rsqrtf(var + BN_EPS);
        ss[c]      = sc;
        ss[64 + c] = beta[c] - mean * sc;
    }
}

__global__ __launch_bounds__(256) void norm_kernel(float* __restrict__ out,
                                                   const float* __restrict__ ss) {
    int i = blockIdx.x * 256 + threadIdx.x;
    float4 v = ((float4*)out)[i];
    int oc = (i >> 8) & 63;
    float sc = ss[oc];
    float sh = ss[64 + oc];
    v.x = fminf(1.0f, fmaxf(-1.0f, fmaf(v.x, sc, sh)));
    v.y = fminf(1.0f, fmaxf(-1.0f, fmaf(v.y, sc, sh)));
    v.z = fminf(1.0f, fmaxf(-1.0f, fmaf(v.z, sc, sh)));
    v.w = fminf(1.0f, fmaxf(-1.0f, fmaf(v.w, sc, sh)));
    ((float4*)out)[i] = v;
}

// ---------------------------------------------------------------------------
extern "C" void kernel_launch(void* const* d_in, const int* in_sizes, int n_in,
                              void* d_out, int out_size, void* d_ws, size_t ws_size,
                              hipStream_t stream) {
    const float* x     = (const float*)d_in[0];
    const float* w     = (const float*)d_in[1];
    const float* gamma = (const float*)d_in[2];
    const float* beta  = (const float*)d_in[3];
    float* out = (float*)d_out;

    char*  wfrag    = (char*)d_ws;                          // 147456 B
    float* partials = (float*)((char*)d_ws + 147456);       // 128*512 floats
    float* ss       = partials + 128 * NBLK;                // 128 floats

    hipLaunchKernelGGL(prep_kernel, dim3(144), dim3(256), 0, stream, w, wfrag);
    hipLaunchKernelGGL(conv_kernel, dim3(8, 64), dim3(512), 0, stream, x, wfrag, out, partials);
    hipLaunchKernelGGL(stats_kernel, dim3(64), dim3(512), 0, stream, partials, gamma, beta, ss);
    hipLaunchKernelGGL(norm_kernel, dim3(4096), dim3(256), 0, stream, out, ss);
}

// Round 11
// 41.240 us; speedup vs baseline: 4.2106x; 4.2106x over previous
//
#include <hip/hip_runtime.h>

// ---------------------------------------------------------------------------
// ConvBlock: y = clip(BN(tr(conv3x3(x^2, Wconv))), -1, 1)
// Wconv[oc][c][di][dj] = weight[oc>>3][(c*9+3di+dj)>>3][(oc-(c*9+3di+dj))&7]
// GEMM: A = Wconv (M=64 oc), B = im2col(x^2) (N=65536 px), K=576.
// bf16 MFMA 32x32x16, 3-pass hi/lo split.
// Round 11: 256-thr blocks (4 waves = wmt x kh), 2-row tiles, 1024 blocks,
// 4 blocks/CU. Conflict-free b128 staging writes (granule-per-thread).
// Symmetric kh merge: every wave finishes one full row -> balanced epilogue.
// ---------------------------------------------------------------------------

#define A_MORR 0.8578f
#define R_MORR 0.8578f
#define TR_C1 (A_MORR * A_MORR + R_MORR * R_MORR)
#define TR_C2 (-2.0f * A_MORR * R_MORR)
#define TR_C3 (1.0f + (A_MORR * R_MORR) * (A_MORR * R_MORR))
#define BN_EPS 1e-5f

#define NPIX 65536
#define X2_LO 17408          // 4*34*128: lo plane offset
#define SMEM_BYTES 34816
#define NBLK 1024            // conv grid size (16 x 64)

typedef __attribute__((ext_vector_type(8))) short bf16x8;
typedef __attribute__((ext_vector_type(16))) float f32x16;

__device__ __forceinline__ void bf16split(float s, unsigned short& h, unsigned short& l) {
    union { float f; unsigned u; } cv; cv.f = s;
    unsigned r = (cv.u + 0x7fffu + ((cv.u >> 16) & 1u)) & 0xffff0000u;
    h = (unsigned short)(r >> 16);
    union { unsigned u; float f; } hv; hv.u = r;
    float lo = s - hv.f;
    cv.f = lo;
    unsigned r2 = cv.u + 0x7fffu + ((cv.u >> 16) & 1u);
    l = (unsigned short)(r2 >> 16);
}

// ---------------------------------------------------------------------------
// Kernel A: fragment-ready bf16 hi/lo weights.
// wfrag[off*8 + ks*2 + mt][prec][lane][8ch] : 72 * 2048 B
// ---------------------------------------------------------------------------
__global__ __launch_bounds__(256) void prep_kernel(const float* __restrict__ w,
                                                   char* __restrict__ wfrag) {
    int gtid = blockIdx.x * 256 + threadIdx.x;
    if (gtid < 36864) {
        int j    = gtid & 7;
        int lane = (gtid >> 3) & 63;
        int okm  = gtid >> 9;
        int mt   = okm & 1;
        int ks   = (okm >> 1) & 3;
        int off  = okm >> 3;
        int oc   = mt * 32 + (lane & 31);
        int c    = ks * 16 + (lane >> 5) * 8 + j;
        int kg   = c * 9 + off;
        float val = w[(oc >> 3) * 576 + (kg >> 3) * 8 + ((oc - kg) & 7)];
        unsigned short h, l;
        bf16split(val, h, l);
        ((unsigned short*)(wfrag + okm * 2048))[lane * 8 + j] = h;
        ((unsigned short*)(wfrag + okm * 2048 + 1024))[lane * 8 + j] = l;
    }
}

// ---------------------------------------------------------------------------
// Kernel B: MFMA conv + tr; per-block BN partials.
// grid (16,64) = 1024 blocks, block 256 (4 waves: wmt x kh), 4 blocks/CU.
// Block tile: 64 oc x 64 px (2 image rows rt*2, rt*2+1).
// Wave (wmt,kh): 32 oc x 64 px over K-half kh; after merge each wave owns
// the FULL-K phi of row kh and does that row's epilogue.
// LDS x2: [4 rows][34 cols][64 ch] bf16 hi+lo, granule swizzle g = q^(c&7):
//   byte(prec,r,c,ch) = prec*17408 + ((r*34+c)<<7) + (((ch>>3)^(c&7))<<4) + (ch&7)*2
// Staging: thread owns one granule (8ch x 1col) -> ds_write_b128 conflict-free.
// ---------------------------------------------------------------------------
__global__ __launch_bounds__(256, 4) void conv_kernel(const float* __restrict__ x,
                                                      const char* __restrict__ wfrag,
                                                      float* __restrict__ out,
                                                      float* __restrict__ partials) {
    const int rt  = blockIdx.x;          // 2-row tile 0..15
    const int b   = blockIdx.y;
    const int bid = b * 16 + rt;         // 0..1023
    const int tid = threadIdx.x;

    const int lane = tid & 63;
    const int wv   = tid >> 6;           // 0..3
    const int wmt  = wv & 1;             // oc half
    const int kh   = wv >> 1;            // K half (and later: owned row)
    const int col  = lane & 31;
    const int hs   = lane >> 5;

    __shared__ __align__(16) char smem[SMEM_BYTES];

    // ---- zero halo cols (c=0, c=33): 4 rows x 2 cols x 8 q x 2 planes ----
    if (tid < 128) {
        int pr = tid & 1;
        int q  = (tid >> 1) & 7;
        int rc = tid >> 4;               // 0..7
        int r  = rc >> 1;
        int cc = (rc & 1) ? 33 : 0;
        int g  = q ^ (cc & 7);
        *(uint4*)(smem + pr * X2_LO + ((r * 34 + cc) << 7) + (g << 4)) = uint4{0, 0, 0, 0};
    }

    // ---- stage x^2 hi/lo: thread = (col co, ch-octet qg), rows rt*2-1..rt*2+2 ----
    {
        const int co = tid & 31;         // image col
        const int qg = tid >> 5;         // channel octet 0..7
        const int c  = 1 + co;           // LDS col
        const int gw = (qg ^ (c & 7)) << 4;
        const float* xb = x + (size_t)(b * 64 + qg * 8) * 1024 + co;
#pragma unroll
        for (int r = 0; r < 4; ++r) {
            int gr = rt * 2 - 1 + r;
            float v[8];
#pragma unroll
            for (int j = 0; j < 8; ++j) v[j] = 0.0f;
            if (gr >= 0 && gr < 32) {
#pragma unroll
                for (int j = 0; j < 8; ++j) v[j] = xb[j * 1024 + gr * 32];
            }
            unsigned hp[4], lp[4];
#pragma unroll
            for (int p = 0; p < 4; ++p) {
                unsigned short h0, l0, h1, l1;
                float s0 = v[2 * p] * v[2 * p];
                float s1 = v[2 * p + 1] * v[2 * p + 1];
                bf16split(s0, h0, l0);
                bf16split(s1, h1, l1);
                hp[p] = (unsigned)h0 | ((unsigned)h1 << 16);
                lp[p] = (unsigned)l0 | ((unsigned)l1 << 16);
            }
            char* dst = smem + ((r * 34 + c) << 7) + gw;
            *(uint4*)dst            = uint4{hp[0], hp[1], hp[2], hp[3]};
            *(uint4*)(dst + X2_LO)  = uint4{lp[0], lp[1], lp[2], lp[3]};
        }
    }
    __syncthreads();                     // BAR1: x2 ready

    // ---- K loop: this wave's K-half, rows 0..3 staged, 2 accs (rows kh-agnostic) ----
    f32x16 acc0, acc1;                   // acc0: out row rt*2, acc1: rt*2+1
#pragma unroll
    for (int i = 0; i < 16; ++i) { acc0[i] = 0.f; acc1[i] = 0.f; }

    const char* wbase = wfrag + wmt * 2048 + (size_t)lane * 16;

#pragma unroll
    for (int dj = 0; dj < 3; ++dj) {
        const int c2 = col + dj;
        const int c7 = c2 & 7;
#pragma unroll
        for (int ksi = 0; ksi < 2; ++ksi) {
            const int ks = kh * 2 + ksi;
            const int gg = ((ks * 2 + hs) ^ c7) << 4;
            bf16x8 bh[4], bl[4];
#pragma unroll
            for (int rr = 0; rr < 4; ++rr) {
                const char* sp = smem + ((rr * 34 + c2) << 7) + gg;
                bh[rr] = *(const bf16x8*)sp;
                bl[rr] = *(const bf16x8*)(sp + X2_LO);
            }
#pragma unroll
            for (int di = 0; di < 3; ++di) {
                const char* wp = wbase + (di * 3 + dj) * 16384 + ks * 4096;
                bf16x8 ah = *(const bf16x8*)wp;
                bf16x8 al = *(const bf16x8*)(wp + 1024);
                acc0 = __builtin_amdgcn_mfma_f32_32x32x16_bf16(ah, bh[di],     acc0, 0, 0, 0);
                acc1 = __builtin_amdgcn_mfma_f32_32x32x16_bf16(ah, bh[di + 1], acc1, 0, 0, 0);
                acc0 = __builtin_amdgcn_mfma_f32_32x32x16_bf16(ah, bl[di],     acc0, 0, 0, 0);
                acc1 = __builtin_amdgcn_mfma_f32_32x32x16_bf16(ah, bl[di + 1], acc1, 0, 0, 0);
                acc0 = __builtin_amdgcn_mfma_f32_32x32x16_bf16(al, bh[di],     acc0, 0, 0, 0);
                acc1 = __builtin_amdgcn_mfma_f32_32x32x16_bf16(al, bh[di + 1], acc1, 0, 0, 0);
            }
        }
    }

    // ---- symmetric kh merge: each wave ends with full-K phi of row kh ----
    float* mg = (float*)smem;            // 4 slots x 16 x 64 floats = 16 KB
    __syncthreads();                     // BAR2: x2 reads done
    {
        const int wslot = wmt * 2 + kh;
        if (kh == 0) {
#pragma unroll
            for (int j = 0; j < 16; ++j) mg[(wslot * 16 + j) * 64 + lane] = acc1[j];
        } else {
#pragma unroll
            for (int j = 0; j < 16; ++j) mg[(wslot * 16 + j) * 64 + lane] = acc0[j];
        }
    }
    __syncthreads();                     // BAR3
    f32x16 phi;
    {
        const int rslot = wmt * 2 + (kh ^ 1);
        if (kh == 0) {
#pragma unroll
            for (int j = 0; j < 16; ++j) phi[j] = acc0[j] + mg[(rslot * 16 + j) * 64 + lane];
        } else {
#pragma unroll
            for (int j = 0; j < 16; ++j) phi[j] = acc1[j] + mg[(rslot * 16 + j) * 64 + lane];
        }
    }

    // ---- tr + store (row rt*2+kh) ----
    float tv[16];
    {
        const size_t obase = ((size_t)b * 64 + wmt * 32) * 1024 + (rt * 2 + kh) * 32 + col;
#pragma unroll
        for (int j = 0; j < 16; ++j) {
            float cp = __cosf(phi[j]);
            float t  = fmaf(TR_C2, cp, TR_C1) / fmaf(TR_C2, cp, TR_C3);
            tv[j] = t;
            int ocl = (j & 3) + 8 * (j >> 2) + 4 * hs;
            out[obase + (size_t)ocl * 1024] = t;
        }
    }

    // ---- per-channel partials: red[64][66] (overlaps mg -> barrier first) ----
    float* red1 = (float*)smem;                    // [64][66]
    float* red2 = red1 + 64 * 66;                  // [64][66]
    __syncthreads();                     // BAR4: merge reads done
#pragma unroll
    for (int j = 0; j < 16; ++j) {
        int ocl = (j & 3) + 8 * (j >> 2) + 4 * hs;
        int ri  = (wmt * 32 + ocl) * 66 + kh * 33 + col;
        red1[ri] = tv[j];
        red2[ri] = tv[j] * tv[j];
    }
    __syncthreads();                     // BAR5
    if (tid < 64) {
        float s1 = 0.f, s2 = 0.f;
#pragma unroll
        for (int k = 0; k < 64; ++k) {
            int idx = tid * 66 + (k >> 5) * 33 + (k & 31);
            s1 += red1[idx];
            s2 += red2[idx];
        }
        partials[(size_t)tid * NBLK + bid]        = s1;
        partials[(size_t)(64 + tid) * NBLK + bid] = s2;
    }
}

// ---------------------------------------------------------------------------
// Kernel C: reduce per-block partials -> BN scale/shift. grid 64, block 512.
// ---------------------------------------------------------------------------
__global__ __launch_bounds__(512) void stats_kernel(const float* __restrict__ partials,
                                                    const float* __restrict__ gamma,
                                                    const float* __restrict__ beta,
                                                    float* __restrict__ ss) {
    const int c   = blockIdx.x;          // channel 0..63
    const int tid = threadIdx.x;
    __shared__ float r1[512], r2[512];
    r1[tid] = partials[(size_t)c * NBLK + tid] + partials[(size_t)c * NBLK + 512 + tid];
    r2[tid] = partials[(size_t)(64 + c) * NBLK + tid]
            + partials[(size_t)(64 + c) * NBLK + 512 + tid];
    __syncthreads();
#pragma unroll
    for (int s = 256; s > 0; s >>= 1) {
        if (tid < s) {
            r1[tid] += r1[tid + s];
            r2[tid] += r2[tid + s];
        }
        __syncthreads();
    }
    if (tid == 0) {
        const float invN = 1.0f / (float)NPIX;
        float mean = r1[0] * invN;
        float var  = r2[0] * invN - mean * mean;
        float sc   = gamma[c] * rsqrtf(var + BN_EPS);
        ss[c]      = sc;
        ss[64 + c] = beta[c] - mean * sc;
    }
}

// ---------------------------------------------------------------------------
// Kernel D: in-place normalize + clip (float4)
// ---------------------------------------------------------------------------
__global__ __launch_bounds__(256) void norm_kernel(float* __restrict__ out,
                                                   const float* __restrict__ ss) {
    int i = blockIdx.x * 256 + threadIdx.x;
    float4 v = ((float4*)out)[i];
    int oc = (i >> 8) & 63;
    float sc = ss[oc];
    float sh = ss[64 + oc];
    v.x = fminf(1.0f, fmaxf(-1.0f, fmaf(v.x, sc, sh)));
    v.y = fminf(1.0f, fmaxf(-1.0f, fmaf(v.y, sc, sh)));
    v.z = fminf(1.0f, fmaxf(-1.0f, fmaf(v.z, sc, sh)));
    v.w = fminf(1.0f, fmaxf(-1.0f, fmaf(v.w, sc, sh)));
    ((float4*)out)[i] = v;
}

// ---------------------------------------------------------------------------
extern "C" void kernel_launch(void* const* d_in, const int* in_sizes, int n_in,
                              void* d_out, int out_size, void* d_ws, size_t ws_size,
                              hipStream_t stream) {
    const float* x     = (const float*)d_in[0];
    const float* w     = (const float*)d_in[1];
    const float* gamma = (const float*)d_in[2];
    const float* beta  = (const float*)d_in[3];
    float* out = (float*)d_out;

    char*  wfrag    = (char*)d_ws;                          // 147456 B
    float* partials = (float*)((char*)d_ws + 147456);       // 128*1024 floats = 512 KB
    float* ss       = partials + 128 * NBLK;                // 128 floats

    hipLaunchKernelGGL(prep_kernel, dim3(144), dim3(256), 0, stream, w, wfrag);
    hipLaunchKernelGGL(conv_kernel, dim3(16, 64), dim3(256), 0, stream, x, wfrag, out, partials);
    hipLaunchKernelGGL(stats_kernel, dim3(64), dim3(512), 0, stream, partials, gamma, beta, ss);
    hipLaunchKernelGGL(norm_kernel, dim3(4096), dim3(256), 0, stream, out, ss);
}

// Round 12
// 41.086 us; speedup vs baseline: 4.2264x; 1.0038x over previous
//
#include <hip/hip_runtime.h>
#include <hip/hip_cooperative_groups.h>

namespace cg = cooperative_groups;

// ---------------------------------------------------------------------------
// ConvBlock: y = clip(BN(tr(conv3x3(x^2, Wconv))), -1, 1)
// Wconv[oc][c][di][dj] = weight[oc>>3][(c*9+3di+dj)>>3][(oc-(c*9+3di+dj))&7]
// GEMM: A = Wconv (M=64 oc), B = im2col(x^2) (N=65536 px), K=576.
// bf16 MFMA 32x32x16, 3-pass hi/lo split.
// Round 12: r11 structure (256-thr blocks, 4 waves = wmt x kh, 2-row tiles,
// 1024 blocks, 4/CU) + FUSED BN/clip via cooperative grid sync (2 syncs):
//   partials -> sync -> blocks 0..63 reduce ss -> sync -> in-reg BN -> store.
// Fallback (occupancy query + launch check): de-fused stats+norm kernels.
// ---------------------------------------------------------------------------

#define A_MORR 0.8578f
#define R_MORR 0.8578f
#define TR_C1 (A_MORR * A_MORR + R_MORR * R_MORR)
#define TR_C2 (-2.0f * A_MORR * R_MORR)
#define TR_C3 (1.0f + (A_MORR * R_MORR) * (A_MORR * R_MORR))
#define BN_EPS 1e-5f

#define NPIX 65536
#define X2_LO 17408          // 4*34*128: lo plane offset
#define SMEM_BYTES 34816
#define NBLK 1024            // conv grid size (16 x 64)

typedef __attribute__((ext_vector_type(8))) short bf16x8;
typedef __attribute__((ext_vector_type(16))) float f32x16;

__device__ __forceinline__ void bf16split(float s, unsigned short& h, unsigned short& l) {
    union { float f; unsigned u; } cv; cv.f = s;
    unsigned r = (cv.u + 0x7fffu + ((cv.u >> 16) & 1u)) & 0xffff0000u;
    h = (unsigned short)(r >> 16);
    union { unsigned u; float f; } hv; hv.u = r;
    float lo = s - hv.f;
    cv.f = lo;
    unsigned r2 = cv.u + 0x7fffu + ((cv.u >> 16) & 1u);
    l = (unsigned short)(r2 >> 16);
}

__device__ __forceinline__ void agst(float* p, float v) {
    __hip_atomic_store(p, v, __ATOMIC_RELAXED, __HIP_MEMORY_SCOPE_AGENT);
}
__device__ __forceinline__ float agld(const float* p) {
    return __hip_atomic_load(p, __ATOMIC_RELAXED, __HIP_MEMORY_SCOPE_AGENT);
}

// ---------------------------------------------------------------------------
// Kernel A: fragment-ready bf16 hi/lo weights.
// wfrag[off*8 + ks*2 + mt][prec][lane][8ch] : 72 * 2048 B
// ---------------------------------------------------------------------------
__global__ __launch_bounds__(256) void prep_kernel(const float* __restrict__ w,
                                                   char* __restrict__ wfrag) {
    int gtid = blockIdx.x * 256 + threadIdx.x;
    if (gtid < 36864) {
        int j    = gtid & 7;
        int lane = (gtid >> 3) & 63;
        int okm  = gtid >> 9;
        int mt   = okm & 1;
        int ks   = (okm >> 1) & 3;
        int off  = okm >> 3;
        int oc   = mt * 32 + (lane & 31);
        int c    = ks * 16 + (lane >> 5) * 8 + j;
        int kg   = c * 9 + off;
        float val = w[(oc >> 3) * 576 + (kg >> 3) * 8 + ((oc - kg) & 7)];
        unsigned short h, l;
        bf16split(val, h, l);
        ((unsigned short*)(wfrag + okm * 2048))[lane * 8 + j] = h;
        ((unsigned short*)(wfrag + okm * 2048 + 1024))[lane * 8 + j] = l;
    }
}

// ---------------------------------------------------------------------------
// Kernel B: MFMA conv + tr (+ fused BN when FUSED=1).
// grid (16,64) = 1024 blocks, block 256 (4 waves: wmt x kh), 4 blocks/CU.
// Block tile: 64 oc x 64 px (2 image rows). After symmetric kh merge each
// wave owns full-K phi of row rt*2+kh and does that row's epilogue.
// LDS x2: [4 rows][34 cols][64 ch] bf16 hi+lo, granule swizzle g = q^(c&7).
// Staging: thread owns one granule (8ch x 1col) -> ds_write_b128 conflict-free.
// ---------------------------------------------------------------------------
template <int FUSED>
__global__ __launch_bounds__(256, 4) void conv_kernel(const float* __restrict__ x,
                                                      const char* __restrict__ wfrag,
                                                      float* __restrict__ out,
                                                      float* __restrict__ partials,
                                                      float* __restrict__ ss,
                                                      const float* __restrict__ gamma,
                                                      const float* __restrict__ beta) {
    const int rt  = blockIdx.x;          // 2-row tile 0..15
    const int b   = blockIdx.y;
    const int bid = b * 16 + rt;         // 0..1023
    const int tid = threadIdx.x;

    const int lane = tid & 63;
    const int wv   = tid >> 6;           // 0..3
    const int wmt  = wv & 1;             // oc half
    const int kh   = wv >> 1;            // K half / owned row
    const int col  = lane & 31;
    const int hs   = lane >> 5;

    __shared__ __align__(16) char smem[SMEM_BYTES];

    // ---- zero halo cols (c=0, c=33) ----
    if (tid < 128) {
        int pr = tid & 1;
        int q  = (tid >> 1) & 7;
        int rc = tid >> 4;               // 0..7
        int r  = rc >> 1;
        int cc = (rc & 1) ? 33 : 0;
        int g  = q ^ (cc & 7);
        *(uint4*)(smem + pr * X2_LO + ((r * 34 + cc) << 7) + (g << 4)) = uint4{0, 0, 0, 0};
    }

    // ---- stage x^2 hi/lo: thread = (col, ch-octet), rows rt*2-1..rt*2+2 ----
    {
        const int co = tid & 31;
        const int qg = tid >> 5;
        const int c  = 1 + co;
        const int gw = (qg ^ (c & 7)) << 4;
        const float* xb = x + (size_t)(b * 64 + qg * 8) * 1024 + co;
#pragma unroll
        for (int r = 0; r < 4; ++r) {
            int gr = rt * 2 - 1 + r;
            float v[8];
#pragma unroll
            for (int j = 0; j < 8; ++j) v[j] = 0.0f;
            if (gr >= 0 && gr < 32) {
#pragma unroll
                for (int j = 0; j < 8; ++j) v[j] = xb[j * 1024 + gr * 32];
            }
            unsigned hp[4], lp[4];
#pragma unroll
            for (int p = 0; p < 4; ++p) {
                unsigned short h0, l0, h1, l1;
                float s0 = v[2 * p] * v[2 * p];
                float s1 = v[2 * p + 1] * v[2 * p + 1];
                bf16split(s0, h0, l0);
                bf16split(s1, h1, l1);
                hp[p] = (unsigned)h0 | ((unsigned)h1 << 16);
                lp[p] = (unsigned)l0 | ((unsigned)l1 << 16);
            }
            char* dst = smem + ((r * 34 + c) << 7) + gw;
            *(uint4*)dst            = uint4{hp[0], hp[1], hp[2], hp[3]};
            *(uint4*)(dst + X2_LO)  = uint4{lp[0], lp[1], lp[2], lp[3]};
        }
    }
    __syncthreads();                     // BAR1: x2 ready

    // ---- K loop: this wave's K-half ----
    f32x16 acc0, acc1;
#pragma unroll
    for (int i = 0; i < 16; ++i) { acc0[i] = 0.f; acc1[i] = 0.f; }

    const char* wbase = wfrag + wmt * 2048 + (size_t)lane * 16;

#pragma unroll
    for (int dj = 0; dj < 3; ++dj) {
        const int c2 = col + dj;
        const int c7 = c2 & 7;
#pragma unroll
        for (int ksi = 0; ksi < 2; ++ksi) {
            const int ks = kh * 2 + ksi;
            const int gg = ((ks * 2 + hs) ^ c7) << 4;
            bf16x8 bh[4], bl[4];
#pragma unroll
            for (int rr = 0; rr < 4; ++rr) {
                const char* sp = smem + ((rr * 34 + c2) << 7) + gg;
                bh[rr] = *(const bf16x8*)sp;
                bl[rr] = *(const bf16x8*)(sp + X2_LO);
            }
#pragma unroll
            for (int di = 0; di < 3; ++di) {
                const char* wp = wbase + (di * 3 + dj) * 16384 + ks * 4096;
                bf16x8 ah = *(const bf16x8*)wp;
                bf16x8 al = *(const bf16x8*)(wp + 1024);
                acc0 = __builtin_amdgcn_mfma_f32_32x32x16_bf16(ah, bh[di],     acc0, 0, 0, 0);
                acc1 = __builtin_amdgcn_mfma_f32_32x32x16_bf16(ah, bh[di + 1], acc1, 0, 0, 0);
                acc0 = __builtin_amdgcn_mfma_f32_32x32x16_bf16(ah, bl[di],     acc0, 0, 0, 0);
                acc1 = __builtin_amdgcn_mfma_f32_32x32x16_bf16(ah, bl[di + 1], acc1, 0, 0, 0);
                acc0 = __builtin_amdgcn_mfma_f32_32x32x16_bf16(al, bh[di],     acc0, 0, 0, 0);
                acc1 = __builtin_amdgcn_mfma_f32_32x32x16_bf16(al, bh[di + 1], acc1, 0, 0, 0);
            }
        }
    }

    // ---- symmetric kh merge: each wave ends with full-K phi of row kh ----
    float* mg = (float*)smem;            // 4 slots x 16 x 64 floats
    __syncthreads();                     // BAR2: x2 reads done
    {
        const int wslot = wmt * 2 + kh;
        if (kh == 0) {
#pragma unroll
            for (int j = 0; j < 16; ++j) mg[(wslot * 16 + j) * 64 + lane] = acc1[j];
        } else {
#pragma unroll
            for (int j = 0; j < 16; ++j) mg[(wslot * 16 + j) * 64 + lane] = acc0[j];
        }
    }
    __syncthreads();                     // BAR3
    f32x16 phi;
    {
        const int rslot = wmt * 2 + (kh ^ 1);
        if (kh == 0) {
#pragma unroll
            for (int j = 0; j < 16; ++j) phi[j] = acc0[j] + mg[(rslot * 16 + j) * 64 + lane];
        } else {
#pragma unroll
            for (int j = 0; j < 16; ++j) phi[j] = acc1[j] + mg[(rslot * 16 + j) * 64 + lane];
        }
    }

    // ---- tr (kept in registers) ----
    float tv[16];
#pragma unroll
    for (int j = 0; j < 16; ++j) {
        float cp = __cosf(phi[j]);
        tv[j] = fmaf(TR_C2, cp, TR_C1) / fmaf(TR_C2, cp, TR_C3);
    }

    // ---- per-channel partials: red[64][66] ----
    float* red1 = (float*)smem;                    // [64][66]
    float* red2 = red1 + 64 * 66;                  // [64][66]
    __syncthreads();                     // BAR4: merge reads done
#pragma unroll
    for (int j = 0; j < 16; ++j) {
        int ocl = (j & 3) + 8 * (j >> 2) + 4 * hs;
        int ri  = (wmt * 32 + ocl) * 66 + kh * 33 + col;
        red1[ri] = tv[j];
        red2[ri] = tv[j] * tv[j];
    }
    __syncthreads();                     // BAR5
    if (tid < 64) {
        float s1 = 0.f, s2 = 0.f;
#pragma unroll
        for (int k = 0; k < 64; ++k) {
            int idx = tid * 66 + (k >> 5) * 33 + (k & 31);
            s1 += red1[idx];
            s2 += red2[idx];
        }
        if (FUSED) {
            agst(&partials[(size_t)tid * NBLK + bid], s1);
            agst(&partials[(size_t)(64 + tid) * NBLK + bid], s2);
        } else {
            partials[(size_t)tid * NBLK + bid]        = s1;
            partials[(size_t)(64 + tid) * NBLK + bid] = s2;
        }
    }

    if constexpr (FUSED) {
        // ---- sync 1: all partials visible; blocks 0..63 reduce one channel ----
        cg::this_grid().sync();
        if (bid < 64) {
            float s1 = 0.f, s2 = 0.f;
            for (int k = tid; k < NBLK; k += 256) {
                s1 += agld(&partials[(size_t)bid * NBLK + k]);
                s2 += agld(&partials[(size_t)(64 + bid) * NBLK + k]);
            }
            float* q1 = (float*)smem;          // 256
            float* q2 = q1 + 256;              // 256
            q1[tid] = s1;
            q2[tid] = s2;
            __syncthreads();
#pragma unroll
            for (int s = 128; s > 0; s >>= 1) {
                if (tid < s) { q1[tid] += q1[tid + s]; q2[tid] += q2[tid + s]; }
                __syncthreads();
            }
            if (tid == 0) {
                const float invN = 1.0f / (float)NPIX;
                float mean = q1[0] * invN;
                float var  = q2[0] * invN - mean * mean;
                float sc   = gamma[bid] * rsqrtf(var + BN_EPS);
                agst(&ss[bid], sc);
                agst(&ss[64 + bid], beta[bid] - mean * sc);
            }
        }
        // ---- sync 2: ss ready; normalize in-register, store once ----
        cg::this_grid().sync();
        float* ssb = (float*)(smem + 33792);       // 128 floats
        if (tid < 128) ssb[tid] = agld(&ss[tid]);
        __syncthreads();

        const size_t obase = ((size_t)b * 64 + wmt * 32) * 1024 + (rt * 2 + kh) * 32 + col;
#pragma unroll
        for (int j = 0; j < 16; ++j) {
            int ocl  = (j & 3) + 8 * (j >> 2) + 4 * hs;
            float sc = ssb[wmt * 32 + ocl];
            float sh = ssb[64 + wmt * 32 + ocl];
            float y  = fminf(1.0f, fmaxf(-1.0f, fmaf(tv[j], sc, sh)));
            out[obase + (size_t)ocl * 1024] = y;
        }
    } else {
        // ---- store raw tr; BN applied by separate kernels ----
        const size_t obase = ((size_t)b * 64 + wmt * 32) * 1024 + (rt * 2 + kh) * 32 + col;
#pragma unroll
        for (int j = 0; j < 16; ++j) {
            int ocl = (j & 3) + 8 * (j >> 2) + 4 * hs;
            out[obase + (size_t)ocl * 1024] = tv[j];
        }
    }
}

// ---------------------------------------------------------------------------
// Fallback kernels
// ---------------------------------------------------------------------------
__global__ __launch_bounds__(512) void stats_kernel(const float* __restrict__ partials,
                                                    const float* __restrict__ gamma,
                                                    const float* __restrict__ beta,
                                                    float* __restrict__ ss) {
    const int c   = blockIdx.x;
    const int tid = threadIdx.x;
    __shared__ float r1[512], r2[512];
    r1[tid] = partials[(size_t)c * NBLK + tid] + partials[(size_t)c * NBLK + 512 + tid];
    r2[tid] = partials[(size_t)(64 + c) * NBLK + tid]
            + partials[(size_t)(64 + c) * NBLK + 512 + tid];
    __syncthreads();
#pragma unroll
    for (int s = 256; s > 0; s >>= 1) {
        if (tid < s) { r1[tid] += r1[tid + s]; r2[tid] += r2[tid + s]; }
        __syncthreads();
    }
    if (tid == 0) {
        const float invN = 1.0f / (float)NPIX;
        float mean = r1[0] * invN;
        float var  = r2[0] * invN - mean * mean;
        float sc   = gamma[c] * rsqrtf(var + BN_EPS);
        ss[c]      = sc;
        ss[64 + c] = beta[c] - mean * sc;
    }
}

__global__ __launch_bounds__(256) void norm_kernel(float* __restrict__ out,
                                                   const float* __restrict__ ss) {
    int i = blockIdx.x * 256 + threadIdx.x;
    float4 v = ((float4*)out)[i];
    int oc = (i >> 8) & 63;
    float sc = ss[oc];
    float sh = ss[64 + oc];
    v.x = fminf(1.0f, fmaxf(-1.0f, fmaf(v.x, sc, sh)));
    v.y = fminf(1.0f, fmaxf(-1.0f, fmaf(v.y, sc, sh)));
    v.z = fminf(1.0f, fmaxf(-1.0f, fmaf(v.z, sc, sh)));
    v.w = fminf(1.0f, fmaxf(-1.0f, fmaf(v.w, sc, sh)));
    ((float4*)out)[i] = v;
}

// ---------------------------------------------------------------------------
extern "C" void kernel_launch(void* const* d_in, const int* in_sizes, int n_in,
                              void* d_out, int out_size, void* d_ws, size_t ws_size,
                              hipStream_t stream) {
    const float* x     = (const float*)d_in[0];
    const float* w     = (const float*)d_in[1];
    const float* gamma = (const float*)d_in[2];
    const float* beta  = (const float*)d_in[3];
    float* out = (float*)d_out;

    char*  wfrag    = (char*)d_ws;                          // 147456 B
    float* partials = (float*)((char*)d_ws + 147456);       // 128*1024 floats
    float* ss       = partials + 128 * NBLK;                // 128 floats

    hipLaunchKernelGGL(prep_kernel, dim3(144), dim3(256), 0, stream, w, wfrag);

    int maxb = 0;
    hipError_t qe = hipOccupancyMaxActiveBlocksPerMultiprocessor(
        &maxb, reinterpret_cast<const void*>(&conv_kernel<1>), 256, 0);
    bool fused = (qe == hipSuccess) && (maxb >= 4);

    if (fused) {
        void* cargs[] = { (void*)&x, (void*)&wfrag, (void*)&out, (void*)&partials,
                          (void*)&ss, (void*)&gamma, (void*)&beta };
        hipError_t le = hipLaunchCooperativeKernel(
            reinterpret_cast<const void*>(&conv_kernel<1>),
            dim3(16, 64), dim3(256), cargs, 0, stream);
        if (le != hipSuccess) fused = false;
    }
    if (!fused) {
        hipLaunchKernelGGL(conv_kernel<0>, dim3(16, 64), dim3(256), 0, stream,
                           x, wfrag, out, partials, ss, gamma, beta);
        hipLaunchKernelGGL(stats_kernel, dim3(64), dim3(512), 0, stream,
                           partials, gamma, beta, ss);
        hipLaunchKernelGGL(norm_kernel, dim3(4096), dim3(256), 0, stream, out, ss);
    }
}